// Round 1
// baseline (515.572 us; speedup 1.0000x reference)
//
#include <hip/hip_runtime.h>
#include <math.h>

// Problem: heatmaps [N=16, J=24, D=64, H=64, W=64] fp32.
// Softmax over flattened D*H*W per (n,j) slab, then soft-argmax marginals:
// out[n,j,0..2] = (E[w], E[h], E[d]) / 64 - 0.5
//
// Strategy: single-pass online softmax fused with weighted coordinate sums.
// HBM-bound: 402.7 MB read once -> ~64 us floor at 6.3 TB/s.

#define SLABS       384        // 16*24
#define SLAB_ELEMS  262144     // 64^3
#define CHUNKS      4          // blocks per slab
#define BLOCK       256
#define CHUNK_ELEMS (SLAB_ELEMS / CHUNKS)   // 65536
#define ITERS       (CHUNK_ELEMS / (BLOCK * 4))  // 64 float4 iters per thread

__device__ __forceinline__ float fast_exp2(float x) {
#if __has_builtin(__builtin_amdgcn_exp2f)
    return __builtin_amdgcn_exp2f(x);
#else
    return exp2f(x);
#endif
}

// Combine two online-softmax tuples (log2-domain max ml, sums S, Sx, Sy, Sz).
__device__ __forceinline__ void combine(float& ml, float& S, float& Sx, float& Sy, float& Sz,
                                        float oml, float oS, float oSx, float oSy, float oSz) {
    float nml = fmaxf(ml, oml);
    float sa = fast_exp2(ml - nml);
    float sb = fast_exp2(oml - nml);
    S  = S * sa  + oS * sb;
    Sx = Sx * sa + oSx * sb;
    Sy = Sy * sa + oSy * sb;
    Sz = Sz * sa + oSz * sb;
    ml = nml;
}

__global__ __launch_bounds__(BLOCK) void jir_partial_kernel(const float* __restrict__ in,
                                                            float* __restrict__ ws) {
    const int slab  = blockIdx.x / CHUNKS;
    const int chunk = blockIdx.x % CHUNKS;
    const float* base = in + (size_t)slab * SLAB_ELEMS + (size_t)chunk * CHUNK_ELEMS;
    const int tid = threadIdx.x;

    const float LOG2E = 1.4426950408889634f;

    float ml = -INFINITY;   // running max, already scaled by log2(e)
    float S = 0.f, Sx = 0.f, Sy = 0.f, Sz = 0.f;

    const int idx0 = chunk * CHUNK_ELEMS;  // flat index of chunk start within slab

#pragma unroll 4
    for (int it = 0; it < ITERS; ++it) {
        const int vi = it * BLOCK + tid;               // float4 index within chunk
        const float4 v = ((const float4*)base)[vi];
        const int idx = idx0 + vi * 4;                 // flat index within slab
        // 4 consecutive elements: same (d,h), w = w0..w0+3 (w0 = idx&63, idx%4==0, so w0<=60)
        const float w0 = (float)(idx & 63);
        const float hh = (float)((idx >> 6) & 63);
        const float dd = (float)(idx >> 12);

        const float vmax = fmaxf(fmaxf(v.x, v.y), fmaxf(v.z, v.w));
        const float nml = vmax * LOG2E;
        if (nml > ml) {
            const float scale = fast_exp2(ml - nml);   // ml=-inf first time -> scale=0
            S *= scale; Sx *= scale; Sy *= scale; Sz *= scale;
            ml = nml;
        }
        const float e0 = fast_exp2(__builtin_fmaf(v.x, LOG2E, -ml));
        const float e1 = fast_exp2(__builtin_fmaf(v.y, LOG2E, -ml));
        const float e2 = fast_exp2(__builtin_fmaf(v.z, LOG2E, -ml));
        const float e3 = fast_exp2(__builtin_fmaf(v.w, LOG2E, -ml));
        const float s = (e0 + e1) + (e2 + e3);
        S  += s;
        Sx += s * w0 + (e1 + 2.f * e2 + 3.f * e3);
        Sy += s * hh;
        Sz += s * dd;
    }

    // Wave-level butterfly reduction over 64 lanes.
#pragma unroll
    for (int off = 1; off < 64; off <<= 1) {
        float oml = __shfl_xor(ml, off, 64);
        float oS  = __shfl_xor(S,  off, 64);
        float oSx = __shfl_xor(Sx, off, 64);
        float oSy = __shfl_xor(Sy, off, 64);
        float oSz = __shfl_xor(Sz, off, 64);
        combine(ml, S, Sx, Sy, Sz, oml, oS, oSx, oSy, oSz);
    }

    // Cross-wave combine through LDS (4 waves per block).
    __shared__ float red[4][5];
    const int wave = tid >> 6;
    const int lane = tid & 63;
    if (lane == 0) {
        red[wave][0] = ml; red[wave][1] = S; red[wave][2] = Sx;
        red[wave][3] = Sy; red[wave][4] = Sz;
    }
    __syncthreads();
    if (tid == 0) {
        float fml = red[0][0], fS = red[0][1], fSx = red[0][2], fSy = red[0][3], fSz = red[0][4];
#pragma unroll
        for (int wv = 1; wv < 4; ++wv) {
            combine(fml, fS, fSx, fSy, fSz,
                    red[wv][0], red[wv][1], red[wv][2], red[wv][3], red[wv][4]);
        }
        float* o = ws + (size_t)blockIdx.x * 5;
        o[0] = fml; o[1] = fS; o[2] = fSx; o[3] = fSy; o[4] = fSz;
    }
}

__global__ __launch_bounds__(64) void jir_finalize_kernel(const float* __restrict__ ws,
                                                          float* __restrict__ out) {
    const int slab = blockIdx.x * 64 + threadIdx.x;
    if (slab >= SLABS) return;

    const float* p0 = ws + (size_t)slab * CHUNKS * 5;
    float ml = p0[0], S = p0[1], Sx = p0[2], Sy = p0[3], Sz = p0[4];
#pragma unroll
    for (int c = 1; c < CHUNKS; ++c) {
        const float* p = p0 + c * 5;
        combine(ml, S, Sx, Sy, Sz, p[0], p[1], p[2], p[3], p[4]);
    }
    const float inv = 1.0f / S;
    out[slab * 3 + 0] = (Sx * inv) * (1.0f / 64.0f) - 0.5f;
    out[slab * 3 + 1] = (Sy * inv) * (1.0f / 64.0f) - 0.5f;
    out[slab * 3 + 2] = (Sz * inv) * (1.0f / 64.0f) - 0.5f;
}

extern "C" void kernel_launch(void* const* d_in, const int* in_sizes, int n_in,
                              void* d_out, int out_size, void* d_ws, size_t ws_size,
                              hipStream_t stream) {
    const float* heatmaps = (const float*)d_in[0];
    float* out = (float*)d_out;
    float* ws = (float*)d_ws;   // SLABS*CHUNKS*5 floats = 30 KB

    jir_partial_kernel<<<SLABS * CHUNKS, BLOCK, 0, stream>>>(heatmaps, ws);
    jir_finalize_kernel<<<(SLABS + 63) / 64, 64, 0, stream>>>(ws, out);
}

// Round 2
// 481.721 us; speedup vs baseline: 1.0703x; 1.0703x over previous
//
#include <hip/hip_runtime.h>
#include <math.h>

// Problem: heatmaps [N=16, J=24, D=64, H=64, W=64] fp32.
// Softmax over flattened D*H*W per (n,j) slab, then soft-argmax marginals:
// out[n,j,0..2] = (E[w], E[h], E[d]) / 64 - 0.5
//
// Single-pass online softmax fused with weighted coordinate sums.
// HBM-bound: 402.7 MB read once -> ~62 us floor at 6.45 TB/s.
// R2: CHUNKS 4->8, 2x float4/iter + explicit prefetch, nontemporal loads,
//     closed-form coordinates (w const/thread, h/d cheap per-iter).

#define SLABS       384        // 16*24
#define SLAB_ELEMS  262144     // 64^3
#define CHUNKS      8          // blocks per slab
#define BLOCK       256
#define CHUNK_ELEMS (SLAB_ELEMS / CHUNKS)         // 32768 elems
#define CHUNK_VEC4  (CHUNK_ELEMS / 4)             // 8192 float4
#define ITERS       (CHUNK_VEC4 / (BLOCK * 2))    // 16 iters x 2 float4/thread

typedef float f32x4 __attribute__((ext_vector_type(4)));

__device__ __forceinline__ float fast_exp2(float x) {
#if __has_builtin(__builtin_amdgcn_exp2f)
    return __builtin_amdgcn_exp2f(x);
#else
    return exp2f(x);
#endif
}

// Combine two online-softmax tuples (log2-domain max ml, sums S, Sx, Sy, Sz).
__device__ __forceinline__ void combine(float& ml, float& S, float& Sx, float& Sy, float& Sz,
                                        float oml, float oS, float oSx, float oSy, float oSz) {
    float nml = fmaxf(ml, oml);
    float sa = fast_exp2(ml - nml);
    float sb = fast_exp2(oml - nml);
    S  = S * sa  + oS * sb;
    Sx = Sx * sa + oSx * sb;
    Sy = Sy * sa + oSy * sb;
    Sz = Sz * sa + oSz * sb;
    ml = nml;
}

__global__ __launch_bounds__(BLOCK) void jir_partial_kernel(const float* __restrict__ in,
                                                            float* __restrict__ ws) {
    const int slab  = blockIdx.x / CHUNKS;
    const int chunk = blockIdx.x % CHUNKS;
    const f32x4* __restrict__ B =
        (const f32x4*)(in + (size_t)slab * SLAB_ELEMS + (size_t)chunk * CHUNK_ELEMS);
    const int tid = threadIdx.x;

    const float LOG2E = 1.4426950408889634f;

    // Coordinates (element flat idx within slab = chunk*32768 + (it*512 + j*256 + tid)*4):
    //   w0 = (4*tid) & 63                       -- constant per thread
    //   h(j=0) = ((it&1)<<5) + (tid>>4),  h(j=1) = h0 + 16   (no mod-64 wrap)
    //   d       = chunk*8 + (it>>1)              -- same for both packs in an iter
    const float w0f   = (float)((4 * tid) & 63);
    const float hbase = (float)(tid >> 4);
    const float dbase = (float)(chunk * 8);

    float ml = -INFINITY;   // running max, pre-scaled by log2(e)
    float S = 0.f, Sx = 0.f, Sy = 0.f, Sz = 0.f;

    f32x4 va = __builtin_nontemporal_load(B + tid);
    f32x4 vb = __builtin_nontemporal_load(B + tid + BLOCK);

#pragma unroll
    for (int it = 0; it < ITERS; ++it) {
        f32x4 na, nb;
        if (it < ITERS - 1) {
            na = __builtin_nontemporal_load(B + (it + 1) * (2 * BLOCK) + tid);
            nb = __builtin_nontemporal_load(B + (it + 1) * (2 * BLOCK) + tid + BLOCK);
        }

        const float h0f = hbase + (float)((it & 1) << 5);
        const float ddf = dbase + (float)(it >> 1);

        const float mA = fmaxf(fmaxf(va.x, va.y), fmaxf(va.z, va.w));
        const float mB = fmaxf(fmaxf(vb.x, vb.y), fmaxf(vb.z, vb.w));
        const float nml = fmaxf(mA, mB) * LOG2E;
        if (nml > ml) {                       // rare after warm-up
            const float scale = fast_exp2(ml - nml);  // ml=-inf first -> 0
            S *= scale; Sx *= scale; Sy *= scale; Sz *= scale;
            ml = nml;
        }

        const float a0 = fast_exp2(__builtin_fmaf(va.x, LOG2E, -ml));
        const float a1 = fast_exp2(__builtin_fmaf(va.y, LOG2E, -ml));
        const float a2 = fast_exp2(__builtin_fmaf(va.z, LOG2E, -ml));
        const float a3 = fast_exp2(__builtin_fmaf(va.w, LOG2E, -ml));
        const float b0 = fast_exp2(__builtin_fmaf(vb.x, LOG2E, -ml));
        const float b1 = fast_exp2(__builtin_fmaf(vb.y, LOG2E, -ml));
        const float b2 = fast_exp2(__builtin_fmaf(vb.z, LOG2E, -ml));
        const float b3 = fast_exp2(__builtin_fmaf(vb.w, LOG2E, -ml));

        const float sA = (a0 + a1) + (a2 + a3);
        const float sB = (b0 + b1) + (b2 + b3);
        const float xA = __builtin_fmaf(3.f, a3, __builtin_fmaf(2.f, a2, a1));
        const float xB = __builtin_fmaf(3.f, b3, __builtin_fmaf(2.f, b2, b1));
        const float sAB = sA + sB;

        S  += sAB;
        Sx  = __builtin_fmaf(sAB, w0f, Sx + (xA + xB));
        Sy  = __builtin_fmaf(sAB, h0f, __builtin_fmaf(16.f, sB, Sy));
        Sz  = __builtin_fmaf(sAB, ddf, Sz);

        va = na; vb = nb;
    }

    // Wave-level butterfly reduction over 64 lanes.
#pragma unroll
    for (int off = 1; off < 64; off <<= 1) {
        float oml = __shfl_xor(ml, off, 64);
        float oS  = __shfl_xor(S,  off, 64);
        float oSx = __shfl_xor(Sx, off, 64);
        float oSy = __shfl_xor(Sy, off, 64);
        float oSz = __shfl_xor(Sz, off, 64);
        combine(ml, S, Sx, Sy, Sz, oml, oS, oSx, oSy, oSz);
    }

    // Cross-wave combine through LDS (4 waves per block).
    __shared__ float red[4][5];
    const int wave = tid >> 6;
    const int lane = tid & 63;
    if (lane == 0) {
        red[wave][0] = ml; red[wave][1] = S; red[wave][2] = Sx;
        red[wave][3] = Sy; red[wave][4] = Sz;
    }
    __syncthreads();
    if (tid == 0) {
        float fml = red[0][0], fS = red[0][1], fSx = red[0][2], fSy = red[0][3], fSz = red[0][4];
#pragma unroll
        for (int wv = 1; wv < 4; ++wv) {
            combine(fml, fS, fSx, fSy, fSz,
                    red[wv][0], red[wv][1], red[wv][2], red[wv][3], red[wv][4]);
        }
        float* o = ws + (size_t)blockIdx.x * 5;
        o[0] = fml; o[1] = fS; o[2] = fSx; o[3] = fSy; o[4] = fSz;
    }
}

__global__ __launch_bounds__(64) void jir_finalize_kernel(const float* __restrict__ ws,
                                                          float* __restrict__ out) {
    const int slab = blockIdx.x * 64 + threadIdx.x;
    if (slab >= SLABS) return;

    const float* p0 = ws + (size_t)slab * CHUNKS * 5;
    float ml = p0[0], S = p0[1], Sx = p0[2], Sy = p0[3], Sz = p0[4];
#pragma unroll
    for (int c = 1; c < CHUNKS; ++c) {
        const float* p = p0 + c * 5;
        combine(ml, S, Sx, Sy, Sz, p[0], p[1], p[2], p[3], p[4]);
    }
    const float inv = 1.0f / S;
    out[slab * 3 + 0] = (Sx * inv) * (1.0f / 64.0f) - 0.5f;
    out[slab * 3 + 1] = (Sy * inv) * (1.0f / 64.0f) - 0.5f;
    out[slab * 3 + 2] = (Sz * inv) * (1.0f / 64.0f) - 0.5f;
}

extern "C" void kernel_launch(void* const* d_in, const int* in_sizes, int n_in,
                              void* d_out, int out_size, void* d_ws, size_t ws_size,
                              hipStream_t stream) {
    const float* heatmaps = (const float*)d_in[0];
    float* out = (float*)d_out;
    float* ws = (float*)d_ws;   // SLABS*CHUNKS*5 floats = 61.4 KB

    jir_partial_kernel<<<SLABS * CHUNKS, BLOCK, 0, stream>>>(heatmaps, ws);
    jir_finalize_kernel<<<(SLABS + 63) / 64, 64, 0, stream>>>(ws, out);
}